// Round 9
// baseline (23.072 us; speedup 1.0000x reference)
//
#include <hip/hip_runtime.h>

// out[b] = SCALE^2 * ( dot(x[b,:], colsum) + sum(bias) ),  colsum[i] = sum_o W[o,i]
// Two plain kernels, no atomics / barriers / memsets / spins:
//   K1: partial[g][c] = sum of W rows [512g, 512g+512) for col c
//       (4 row-groups x 128 col-slices -> 512 blocks x 512 thr, 4 waves/SIMD).
//       Block 0 also writes bsum = sum(bias).
//   K2: 512 blocks x 512 thr; each block reduces partial[4][2048] (32 KB,
//       L2-hot) into LDS wsum; BOTH x rows per wave are prefetched into
//       registers before the barrier so no global latency is exposed after it.
// Cross-kernel visibility via the runtime's end-of-kernel L2 writeback.

constexpr int IN_DIM  = 2048;
constexpr int BATCH   = 8192;
constexpr float SCALE2 = 0.01f;   // SCALE*SCALE
constexpr int DGROUPS = 4;        // partial depth (512 rows each)

// ---------------------------------------------------------------------------
// K1: 512 blocks x 512 threads. Block b: row-group g = b>>7 (512 rows),
// col-slice h = b&127 (16 cols = 4 float4). Thread t: col4 = h*4 + (t&3),
// rsub = t>>2 (0..127), rows g*512 + rsub + 128k, k = 0..3.
// Coalescing: 4 lanes x 16B = 64B (one cache line) per row segment.
// ---------------------------------------------------------------------------
__global__ __launch_bounds__(512)
void colsum_partial(const float* __restrict__ W, const float* __restrict__ bias,
                    float* __restrict__ partial, float* __restrict__ bsum) {
    const int t = threadIdx.x;          // 0..511
    const int b = blockIdx.x;           // 0..511
    const int g = b >> 7;               // 0..3
    const int h = b & 127;              // 0..127
    const int lane = t & 63, w = t >> 6;

    const float4* W4 = reinterpret_cast<const float4*>(W);
    const int c4   = (h << 2) + (t & 3);           // float4 col 0..511
    const int rsub = t >> 2;                       // 0..127
    const size_t base = (size_t)((g << 9) + rsub) * (IN_DIM / 4) + c4;

    float4 acc = {0.f, 0.f, 0.f, 0.f};
    #pragma unroll
    for (int k = 0; k < 4; ++k) {
        const float4 v = W4[base + (size_t)(k << 7) * (IN_DIM / 4)];
        acc.x += v.x; acc.y += v.y; acc.z += v.z; acc.w += v.w;
    }
    // merge rsub bits within the wave (lane bits 2..5); c4 invariant
    #pragma unroll
    for (int m = 4; m <= 32; m <<= 1) {
        acc.x += __shfl_xor(acc.x, m); acc.y += __shfl_xor(acc.y, m);
        acc.z += __shfl_xor(acc.z, m); acc.w += __shfl_xor(acc.w, m);
    }

    __shared__ float4 redA[8][4];       // [wave][col4 within slice]
    if (lane < 4) redA[w][lane] = acc;
    __syncthreads();
    if (t < 4) {                        // one thread per col4 of this slice
        float4 s = redA[0][t];
        #pragma unroll
        for (int j = 1; j < 8; ++j) {
            const float4 v = redA[j][t];
            s.x += v.x; s.y += v.y; s.z += v.z; s.w += v.w;
        }
        reinterpret_cast<float4*>(partial)[(size_t)g * (IN_DIM / 4) + (h << 2) + t] = s;
    }

    if (b == 0) {  // bias sum (concurrent with the rest)
        __shared__ float bs_red[8];
        float s = 0.f;
        #pragma unroll
        for (int k = 0; k < 4; ++k) s += bias[t + (k << 9)];
        #pragma unroll
        for (int off = 32; off; off >>= 1) s += __shfl_down(s, off);
        if (lane == 0) bs_red[w] = s;
        __syncthreads();
        if (t == 0) {
            float tot = 0.f;
            #pragma unroll
            for (int j = 0; j < 8; ++j) tot += bs_red[j];
            bsum[0] = tot;
        }
    }
}

// ---------------------------------------------------------------------------
// K2: 512 blocks x 512 threads (8 waves, 2 blocks/CU -> 4 waves/SIMD).
// All global loads (partial[4][2048] + both x rows) are issued before the
// barrier; after it the kernel is pure LDS reads + FMAs + shuffle reduce.
// __launch_bounds__(512, 4): cap VGPR at 128 so 2 blocks/CU stay resident.
// ---------------------------------------------------------------------------
__global__ __launch_bounds__(512, 4)
void reduce_matvec(const float* __restrict__ x, const float* __restrict__ partial,
                   const float* __restrict__ bsum, float* __restrict__ out) {
    __shared__ float4 wsh4[IN_DIM / 4];   // 8 KB
    __shared__ float  bs_sh;

    const int t    = threadIdx.x;          // 0..511
    const int b    = blockIdx.x;           // 0..511
    const int lane = t & 63;
    const int w    = t >> 6;               // 0..7

    // ---- issue phase-1 loads (partial[4][2048], L2-hot)
    const float4* p4 = reinterpret_cast<const float4*>(partial);
    float4 pv[DGROUPS];
    #pragma unroll
    for (int g = 0; g < DGROUPS; ++g)
        pv[g] = p4[(size_t)g * (IN_DIM / 4) + t];

    // ---- issue BOTH rows' x loads (independent of LDS wsum)
    const float4* x4 = reinterpret_cast<const float4*>(x);
    const int r0 = (b << 4) + (w << 1);
    const size_t xb = (size_t)r0 * (IN_DIM / 4);
    float4 xv0[8], xv1[8];
    #pragma unroll
    for (int k = 0; k < 8; ++k)
        xv0[k] = x4[xb + (k << 6) + lane];
    #pragma unroll
    for (int k = 0; k < 8; ++k)
        xv1[k] = x4[xb + 512 + (k << 6) + lane];

    if (t == 0) bs_sh = bsum[0];

    // ---- reduce partials into LDS wsum
    float4 acc = pv[0];
    #pragma unroll
    for (int g = 1; g < DGROUPS; ++g) {
        acc.x += pv[g].x; acc.y += pv[g].y;
        acc.z += pv[g].z; acc.w += pv[g].w;
    }
    wsh4[t] = acc;
    __syncthreads();

    // ---- phase 2: pure LDS + FMA, no global latency
    float a0 = 0.f, a1 = 0.f;
    #pragma unroll
    for (int k = 0; k < 8; ++k) {
        const float4 wv = wsh4[(k << 6) + lane];
        a0 += xv0[k].x * wv.x + xv0[k].y * wv.y + xv0[k].z * wv.z + xv0[k].w * wv.w;
        a1 += xv1[k].x * wv.x + xv1[k].y * wv.y + xv1[k].z * wv.z + xv1[k].w * wv.w;
    }
    #pragma unroll
    for (int off = 32; off; off >>= 1) {
        a0 += __shfl_down(a0, off);
        a1 += __shfl_down(a1, off);
    }
    if (lane == 0) {
        const float bs = bs_sh;
        *reinterpret_cast<float2*>(out + r0) =
            make_float2(SCALE2 * (a0 + bs), SCALE2 * (a1 + bs));
    }
}

extern "C" void kernel_launch(void* const* d_in, const int* in_sizes, int n_in,
                              void* d_out, int out_size, void* d_ws, size_t ws_size,
                              hipStream_t stream) {
    const float* x    = (const float*)d_in[0];   // [8192, 2048]
    const float* W    = (const float*)d_in[1];   // [2048, 2048]
    const float* bias = (const float*)d_in[2];   // [2048]
    float* out = (float*)d_out;                  // [8192]
    char*  ws  = (char*)d_ws;

    // ws layout: partial[4][2048] (32 KB) | bsum (64 B)
    float* partial = (float*)ws;
    float* bsum    = (float*)(ws + (size_t)DGROUPS * IN_DIM * sizeof(float));

    colsum_partial<<<512, 512, 0, stream>>>(W, bias, partial, bsum);
    reduce_matvec<<<BATCH / 16, 512, 0, stream>>>(x, partial, bsum, out);
}

// Round 11
// 21.577 us; speedup vs baseline: 1.0693x; 1.0693x over previous
//
#include <hip/hip_runtime.h>
#include <hip/hip_cooperative_groups.h>

namespace cg = cooperative_groups;

// out[b] = SCALE^2 * ( dot(x[b,:], colsum) + sum(bias) ),  colsum[i] = sum_o W[o,i]
//
// Primary path: ONE cooperative kernel, 256 blocks x 1024 threads (1 block/CU,
// 4 waves/SIMD), one grid.sync().
//   pre-sync : W colsum partial (block = 256 rows x 64 cols) streams 16 MB,
//              overlapped with x row-0 prefetch into registers (32 MB) and a
//              block-local bias sum.
//   post-sync: reduce partial[8][2048] (LLC-hot) -> LDS wsum, then per wave
//              2-row matvec (row 0 from regs, row 1 streamed).
// Fallback path (if cooperative occupancy/launch fails): the proven round-8
// two-kernel pair. Decision is host-side and deterministic per call.

constexpr int IN_DIM  = 2048;
constexpr int BATCH   = 8192;
constexpr float SCALE2 = 0.01f;   // SCALE*SCALE
constexpr int DGROUPS = 8;        // partial depth (256 rows each)
constexpr int NBLK    = 256;      // cooperative grid: 1 block/CU

// ===========================================================================
// Fused cooperative kernel: 256 blocks x 1024 threads (16 waves).
// ===========================================================================
__global__ __launch_bounds__(1024, 4)
void fused(const float* __restrict__ x, const float* __restrict__ W,
           const float* __restrict__ bias, float* __restrict__ out,
           float* __restrict__ partial) {
    const int t    = threadIdx.x;      // 0..1023
    const int b    = blockIdx.x;       // 0..255
    const int lane = t & 63;
    const int w    = t >> 6;           // 0..15

    __shared__ float4 wsh4[IN_DIM / 4];   // 8 KB
    __shared__ float4 redA[16][16];       // 4 KB
    __shared__ float  bs_red[16];
    __shared__ float  bs_sh;

    // ---- issue W colsum loads: block b = row-group g (256 rows, g=b>>5) x
    // col-slice h (64 cols = 16 float4, h=b&31). Thread: c4 = h*16 + (t&15),
    // rsub = t>>4 (0..63), rows g*256 + rsub + 64k, k=0..3.
    // 16 lanes x 16B = 256B contiguous segments.
    const float4* W4 = reinterpret_cast<const float4*>(W);
    const int g    = b >> 5;
    const int h    = b & 31;
    const int c4   = (h << 4) + (t & 15);         // float4 col 0..511
    const int rsub = t >> 4;                      // 0..63
    const size_t wbase = (size_t)((g << 8) + rsub) * (IN_DIM / 4) + c4;
    const float4 wa0 = W4[wbase];
    const float4 wa1 = W4[wbase + (size_t)64  * (IN_DIM / 4)];
    const float4 wa2 = W4[wbase + (size_t)128 * (IN_DIM / 4)];
    const float4 wa3 = W4[wbase + (size_t)192 * (IN_DIM / 4)];

    // ---- issue x row-0 prefetch (held in regs across the sync)
    const float4* x4 = reinterpret_cast<const float4*>(x);
    const int r0 = (b << 5) + (w << 1);           // wave's first row
    const size_t xb = (size_t)r0 * (IN_DIM / 4);
    float4 xv[8];
    #pragma unroll
    for (int k = 0; k < 8; ++k)
        xv[k] = x4[xb + (k << 6) + lane];

    // ---- block-local bias sum (2048 floats, L2/LLC broadcast)
    float bsv = bias[t] + bias[t + 1024];

    // ---- reduce W partial for this block
    float4 acc = { wa0.x + wa1.x + wa2.x + wa3.x,
                   wa0.y + wa1.y + wa2.y + wa3.y,
                   wa0.z + wa1.z + wa2.z + wa3.z,
                   wa0.w + wa1.w + wa2.w + wa3.w };
    #pragma unroll
    for (int m = 16; m <= 32; m <<= 1) {          // merge rsub bits in-wave
        acc.x += __shfl_xor(acc.x, m); acc.y += __shfl_xor(acc.y, m);
        acc.z += __shfl_xor(acc.z, m); acc.w += __shfl_xor(acc.w, m);
    }
    #pragma unroll
    for (int off = 32; off; off >>= 1) bsv += __shfl_down(bsv, off);
    if (lane < 16) redA[w][lane] = acc;
    if (lane == 0) bs_red[w] = bsv;
    __syncthreads();
    if (t < 16) {                                 // one thread per col4
        float4 s = redA[0][t];
        #pragma unroll
        for (int j = 1; j < 16; ++j) {
            const float4 v = redA[j][t];
            s.x += v.x; s.y += v.y; s.z += v.z; s.w += v.w;
        }
        reinterpret_cast<float4*>(partial)[(size_t)g * (IN_DIM / 4) + (h << 4) + t] = s;
    }
    if (t == 0) {
        float tot = 0.f;
        #pragma unroll
        for (int j = 0; j < 16; ++j) tot += bs_red[j];
        bs_sh = tot;
    }

    cg::this_grid().sync();

    // ---- phase B: reduce partial[8][2048] (LLC-hot) into LDS wsum
    if (t < IN_DIM / 4) {
        const float4* p4 = reinterpret_cast<const float4*>(partial);
        float4 s = p4[(size_t)(b & (DGROUPS - 1)) * (IN_DIM / 4) + t];
        #pragma unroll
        for (int i = 1; i < DGROUPS; ++i) {
            const int g2 = (i + b) & (DGROUPS - 1);   // stagger per block
            const float4 v = p4[(size_t)g2 * (IN_DIM / 4) + t];
            s.x += v.x; s.y += v.y; s.z += v.z; s.w += v.w;
        }
        wsh4[t] = s;
    }
    __syncthreads();

    // ---- phase C: row 0 from prefetched regs, row 1 streamed in-loop
    float a0 = 0.f, a1 = 0.f;
    #pragma unroll
    for (int k = 0; k < 8; ++k) {
        const int ci = (k << 6) + lane;
        const float4 wv = wsh4[ci];
        const float4 v1 = x4[xb + 512 + ci];
        a0 += xv[k].x * wv.x + xv[k].y * wv.y + xv[k].z * wv.z + xv[k].w * wv.w;
        a1 += v1.x * wv.x + v1.y * wv.y + v1.z * wv.z + v1.w * wv.w;
    }
    #pragma unroll
    for (int off = 32; off; off >>= 1) {
        a0 += __shfl_down(a0, off);
        a1 += __shfl_down(a1, off);
    }
    if (lane == 0) {
        const float bs = bs_sh;
        *reinterpret_cast<float2*>(out + r0) =
            make_float2(SCALE2 * (a0 + bs), SCALE2 * (a1 + bs));
    }
}

// ===========================================================================
// Fallback: round-8 two-kernel pair (proven 21.35 us).
// ===========================================================================
__global__ __launch_bounds__(512)
void colsum_partial(const float* __restrict__ W, const float* __restrict__ bias,
                    float* __restrict__ partial, float* __restrict__ bsum) {
    const int t = threadIdx.x;
    const int b = blockIdx.x;
    const int g = b >> 6;               // 0..7
    const int h = b & 63;               // 0..63
    const int lane = t & 63, w = t >> 6;

    const float4* W4 = reinterpret_cast<const float4*>(W);
    const int c4   = (h << 3) + (t & 7);
    const int rsub = t >> 3;
    const size_t base = (size_t)((g << 8) + rsub) * (IN_DIM / 4) + c4;

    float4 acc = {0.f, 0.f, 0.f, 0.f};
    #pragma unroll
    for (int k = 0; k < 4; ++k) {
        const float4 v = W4[base + (size_t)(k << 6) * (IN_DIM / 4)];
        acc.x += v.x; acc.y += v.y; acc.z += v.z; acc.w += v.w;
    }
    #pragma unroll
    for (int m = 8; m <= 32; m <<= 1) {
        acc.x += __shfl_xor(acc.x, m); acc.y += __shfl_xor(acc.y, m);
        acc.z += __shfl_xor(acc.z, m); acc.w += __shfl_xor(acc.w, m);
    }

    __shared__ float4 redA[8][8];
    if (lane < 8) redA[w][lane] = acc;
    __syncthreads();
    if (t < 8) {
        float4 s = redA[0][t];
        #pragma unroll
        for (int j = 1; j < 8; ++j) {
            const float4 v = redA[j][t];
            s.x += v.x; s.y += v.y; s.z += v.z; s.w += v.w;
        }
        reinterpret_cast<float4*>(partial)[(size_t)g * (IN_DIM / 4) + (h << 3) + t] = s;
    }

    if (b == 0) {
        __shared__ float bs_red[8];
        float s = 0.f;
        #pragma unroll
        for (int k = 0; k < 4; ++k) s += bias[t + (k << 9)];
        #pragma unroll
        for (int off = 32; off; off >>= 1) s += __shfl_down(s, off);
        if (lane == 0) bs_red[w] = s;
        __syncthreads();
        if (t == 0) {
            float tot = 0.f;
            #pragma unroll
            for (int j = 0; j < 8; ++j) tot += bs_red[j];
            bsum[0] = tot;
        }
    }
}

__global__ __launch_bounds__(512)
void reduce_matvec(const float* __restrict__ x, const float* __restrict__ partial,
                   const float* __restrict__ bsum, float* __restrict__ out) {
    __shared__ float4 wsh4[IN_DIM / 4];
    __shared__ float  bs_sh;

    const int t    = threadIdx.x;
    const int b    = blockIdx.x;
    const int lane = t & 63;
    const int w    = t >> 6;

    const float4* p4 = reinterpret_cast<const float4*>(partial);
    float4 pv[DGROUPS];
    #pragma unroll
    for (int g = 0; g < DGROUPS; ++g)
        pv[g] = p4[(size_t)g * (IN_DIM / 4) + t];

    const float4* x4 = reinterpret_cast<const float4*>(x);
    const int r0 = (b << 4) + (w << 1);
    const size_t xb = (size_t)r0 * (IN_DIM / 4);
    float4 xv[8];
    #pragma unroll
    for (int k = 0; k < 8; ++k)
        xv[k] = x4[xb + (k << 6) + lane];

    if (t == 0) bs_sh = bsum[0];

    float4 acc = pv[0];
    #pragma unroll
    for (int g = 1; g < DGROUPS; ++g) {
        acc.x += pv[g].x; acc.y += pv[g].y;
        acc.z += pv[g].z; acc.w += pv[g].w;
    }
    wsh4[t] = acc;
    __syncthreads();

    float a0 = 0.f, a1 = 0.f;
    #pragma unroll
    for (int k = 0; k < 8; ++k) {
        const int ci = (k << 6) + lane;
        const float4 wv = wsh4[ci];
        const float4 v1 = x4[xb + 512 + ci];
        a0 += xv[k].x * wv.x + xv[k].y * wv.y + xv[k].z * wv.z + xv[k].w * wv.w;
        a1 += v1.x * wv.x + v1.y * wv.y + v1.z * wv.z + v1.w * wv.w;
    }
    #pragma unroll
    for (int off = 32; off; off >>= 1) {
        a0 += __shfl_down(a0, off);
        a1 += __shfl_down(a1, off);
    }
    if (lane == 0) {
        const float bs = bs_sh;
        *reinterpret_cast<float2*>(out + r0) =
            make_float2(SCALE2 * (a0 + bs), SCALE2 * (a1 + bs));
    }
}

extern "C" void kernel_launch(void* const* d_in, const int* in_sizes, int n_in,
                              void* d_out, int out_size, void* d_ws, size_t ws_size,
                              hipStream_t stream) {
    const float* x    = (const float*)d_in[0];   // [8192, 2048]
    const float* W    = (const float*)d_in[1];   // [2048, 2048]
    const float* bias = (const float*)d_in[2];   // [2048]
    float* out = (float*)d_out;                  // [8192]
    char*  ws  = (char*)d_ws;

    float* partial = (float*)ws;                 // partial[8][2048] = 64 KB
    float* bsum    = (float*)(ws + (size_t)DGROUPS * IN_DIM * sizeof(float));

    // Host-side, capture-safe occupancy check for the cooperative path.
    int occ = 0;
    hipError_t qe = hipOccupancyMaxActiveBlocksPerMultiprocessor(
        &occ, fused, 1024, 0);

    bool coop_ok = (qe == hipSuccess && occ >= 1);
    if (coop_ok) {
        const float* xa = x; const float* Wa = W; const float* ba = bias;
        float* oa = out; float* pa = partial;
        void* args[] = { (void*)&xa, (void*)&Wa, (void*)&ba,
                         (void*)&oa, (void*)&pa };
        hipError_t le = hipLaunchCooperativeKernel(
            (const void*)fused, dim3(NBLK), dim3(1024), args, 0, stream);
        if (le == hipSuccess) return;
        coop_ok = false;                         // fall through to fallback
    }

    // Fallback: proven round-8 two-kernel path.
    colsum_partial<<<512, 512, 0, stream>>>(W, bias, partial, bsum);
    reduce_matvec<<<BATCH / 16, 512, 0, stream>>>(x, partial, bsum, out);
}